// Round 1
// baseline (74.813 us; speedup 1.0000x reference)
//
#include <hip/hip_runtime.h>

#define D 128
#define NS 16
#define BATCH 16384
#define TILE 64
#define CHUNK 512
#define PST 40  // prep LDS row stride (shorts): 16B-aligned, decent bank spread

typedef __attribute__((ext_vector_type(8))) short short8;
typedef __attribute__((ext_vector_type(4))) float f32x4;

__device__ __forceinline__ unsigned short f2bf(float f) {
  unsigned u = __builtin_bit_cast(unsigned, f);
  u += 0x7FFFu + ((u >> 16) & 1u);   // round-to-nearest-even
  return (unsigned short)(u >> 16);
}

__device__ __forceinline__ uint4 pack8(float4 a, float4 b) {
  unsigned short p[8];
  p[0] = f2bf(a.x); p[1] = f2bf(a.y); p[2] = f2bf(a.z); p[3] = f2bf(a.w);
  p[4] = f2bf(b.x); p[5] = f2bf(b.y); p[6] = f2bf(b.z); p[7] = f2bf(b.w);
  return *(const uint4*)p;
}

// ---------------------------------------------------------------------------
// Kernel 0: one-time weight prep.  Wt[(mat*NS+s)*D*D + col*D + row] =
// bf16(M[s][row][col]) — TRANSPOSED so an MFMA B-fragment (8 consecutive k at
// fixed col) is one contiguous 16B load.  128 blocks = 16 s x 2 mat x 4 row
// stripes of 32. LDS tile transpose: coalesced fp32 read, coalesced bf16 write.
// ---------------------------------------------------------------------------
__global__ __launch_bounds__(256, 2) void prep_weights(
    const float* __restrict__ A_all, const float* __restrict__ C_all,
    unsigned short* __restrict__ Wt) {
  __shared__ unsigned short T[D * PST];  // [col][r_local(32)+pad]
  const int b = blockIdx.x;
  const int s = b >> 3, mat = (b >> 2) & 1, r0 = (b & 3) * 32;
  const float* __restrict__ src =
      (mat ? C_all : A_all) + (size_t)s * D * D + (size_t)r0 * D;
  unsigned short* __restrict__ dst = Wt + (size_t)(mat * NS + s) * D * D + r0;
  const int t = threadIdx.x;
  {
    const int r = t >> 3, c0 = (t & 7) * 16;  // 32 rows x 8 threads/row
    const float4* srow = (const float4*)(src + r * D + c0);
#pragma unroll
    for (int i = 0; i < 4; i++) {
      float4 v = srow[i];
      T[(c0 + i * 4 + 0) * PST + r] = f2bf(v.x);
      T[(c0 + i * 4 + 1) * PST + r] = f2bf(v.y);
      T[(c0 + i * 4 + 2) * PST + r] = f2bf(v.z);
      T[(c0 + i * 4 + 3) * PST + r] = f2bf(v.w);
    }
  }
  __syncthreads();
  {
    const int c = t >> 1, rh = (t & 1) * 16;  // 128 cols x 2 threads/col
    const uint4* tsrc = (const uint4*)&T[c * PST + rh];
    uint4* d4 = (uint4*)(dst + (size_t)c * D + rh);
    d4[0] = tsrc[0];
    d4[1] = tsrc[1];
  }
}

// ---------------------------------------------------------------------------
// Kernel 1.  Changes vs R6:
//  - B-frags (A and C) load DIRECTLY global->VGPR from transposed bf16 Wt:
//    16B dwordx4, 64B L2 segments.  No Ws LDS, no staging writes, no 256
//    scalar ds_read_u16, no fp32->bf16 weight packing, one fewer barrier.
//  - 4 waves own DISJOINT 32-col slices (wave w: cols w*32..+31) -> each
//    weight byte loaded once per block (halves L2 weight traffic again).
//  - XH tile XOR-swizzled on 16B chunks: chunk' = chunk ^ (row&15).  aF
//    ds_read_b128 are then perfectly bank-balanced (8 dwords/bank/wave, the
//    minimum) vs 8-way conflicted with the old 136-short stride.
//  MFMA 16x16x32 bf16 layouts (HW-verified):
//    A: A[m=lane&15][k=(lane>>4)*8+j]   B: B[k=(lane>>4)*8+j][n=lane&15]
//    C/D: col=lane&15, row=(lane>>4)*4+reg
//  LDS: XH 16K + rowlist 2K = 18.1K; ~150 VGPR -> 2 blocks/CU (grid=2/CU).
// ---------------------------------------------------------------------------
__global__ __launch_bounds__(256, 2) void ssm_mfma(
    const float* __restrict__ x,
    const int* __restrict__ sidx,
    const unsigned short* __restrict__ Wt,
    float* __restrict__ out) {
  __shared__ unsigned short XH[TILE * D];  // [row][chunk ^ (row&15)][8]
  __shared__ int rowlist[CHUNK];
  __shared__ int wcnt[8];

  const int b = blockIdx.x;
  const int s = (b & 7) | (((b >> 3) & 1) << 3);  // same-state blocks same XCD
  const int c0 = (b >> 4) * CHUNK;
  const int tid = threadIdx.x;
  const int lane = tid & 63, w = tid >> 6;
  const int l15 = lane & 15, quad = lane >> 4;

  // ---- chunk scan loads (issue first; ballots overlap weight loads) ----
  const int v0 = sidx[c0 + tid];
  const int v1 = sidx[c0 + 256 + tid];

  // ---- B-fragments for BOTH phases, direct from Wt (L2-resident) ----
  short8 aW[4][2], cW[4][2];
  {
    const unsigned short* As =
        Wt + (size_t)s * D * D + (w * 32 + l15) * D + quad * 8;
    const unsigned short* Cs = As + NS * D * D;
#pragma unroll
    for (int kb = 0; kb < 4; kb++)
#pragma unroll
      for (int nb = 0; nb < 2; nb++) {
        aW[kb][nb] = *(const short8*)(As + nb * 16 * D + kb * 32);
        cW[kb][nb] = *(const short8*)(Cs + nb * 16 * D + kb * 32);
      }
  }

  // ---- ballot compaction ----
  const unsigned long long lanelt = (1ull << lane) - 1ull;
  const unsigned long long m0 = __ballot(v0 == s);
  const unsigned long long m1 = __ballot(v1 == s);
  if (lane == 0) { wcnt[w] = (int)__popcll(m0); wcnt[4 + w] = (int)__popcll(m1); }
  __syncthreads();
  int pre0 = 0, pre1 = 0, tot0 = 0, cnt = 0;
#pragma unroll
  for (int ww = 0; ww < 4; ww++) {
    if (ww < w) { pre0 += wcnt[ww]; pre1 += wcnt[4 + ww]; }
    tot0 += wcnt[ww];
    cnt += wcnt[ww] + wcnt[4 + ww];
  }
  if (v0 == s) rowlist[pre0 + (int)__popcll(m0 & lanelt)] = c0 + tid;
  if (v1 == s) rowlist[tot0 + pre1 + (int)__popcll(m1 & lanelt)] = c0 + 256 + tid;
  if (cnt == 0) return;  // block-uniform

  // ---- MFMA tiles (typically exactly one: cnt ~ N(32, 5.5)) ----
#pragma unroll 1
  for (int i0 = 0; i0 < cnt; i0 += TILE) {
    __syncthreads();  // rowlist ready / prior-pass XH reads done

    // gather 64 X rows (4 threads/row), swizzled 16B LDS writes
    {
      const int r = tid >> 2, q4 = tid & 3;
      const int rid = (i0 + r < cnt) ? rowlist[i0 + r] : -1;
      if (rid >= 0) {
        const float4* src = (const float4*)(x + (size_t)rid * D + q4 * 32);
#pragma unroll
        for (int i = 0; i < 4; i++) {
          float4 va = src[2 * i];
          float4 vb = src[2 * i + 1];
          *(uint4*)&XH[r * D + (((q4 * 4 + i) ^ (r & 15)) << 3)] = pack8(va, vb);
        }
      } else {
        uint4 z = {0, 0, 0, 0};
#pragma unroll
        for (int i = 0; i < 4; i++)
          *(uint4*)&XH[r * D + (((q4 * 4 + i) ^ (r & 15)) << 3)] = z;
      }
    }
    __syncthreads();

    // phase 1: acc = X @ A ; wave w computes all 64 rows x cols w*32..+31
    f32x4 acc[4][2];
#pragma unroll
    for (int ti = 0; ti < 4; ti++) {
      acc[ti][0] = (f32x4){0.f, 0.f, 0.f, 0.f};
      acc[ti][1] = (f32x4){0.f, 0.f, 0.f, 0.f};
    }
#pragma unroll
    for (int kb = 0; kb < 4; kb++) {
      short8 aF[4];
#pragma unroll
      for (int ti = 0; ti < 4; ti++)
        aF[ti] = *(const short8*)&XH[(ti * 16 + l15) * D +
                                     (((kb * 4 + quad) ^ l15) << 3)];
#pragma unroll
      for (int ti = 0; ti < 4; ti++) {
        acc[ti][0] = __builtin_amdgcn_mfma_f32_16x16x32_bf16(aF[ti], aW[kb][0],
                                                             acc[ti][0], 0, 0, 0);
        acc[ti][1] = __builtin_amdgcn_mfma_f32_16x16x32_bf16(aF[ti], aW[kb][1],
                                                             acc[ti][1], 0, 0, 0);
      }
    }
    __syncthreads();  // all phase-1 XH(X) reads done

    // H = relu(acc) -> XH (aliased over X; swizzle-consistent scalar writes)
#pragma unroll
    for (int ti = 0; ti < 4; ti++)
#pragma unroll
      for (int nb = 0; nb < 2; nb++)
#pragma unroll
        for (int rr = 0; rr < 4; rr++) {
          float v = acc[ti][nb][rr];
          const int row = ti * 16 + quad * 4 + rr;
          const int ch = (w * 4 + nb * 2 + (l15 >> 3)) ^ (quad * 4 + rr);
          XH[row * D + (ch << 3) + (l15 & 7)] = f2bf(v > 0.f ? v : 0.f);
        }
    __syncthreads();

    // phase 2: out = H @ C
#pragma unroll
    for (int ti = 0; ti < 4; ti++) {
      acc[ti][0] = (f32x4){0.f, 0.f, 0.f, 0.f};
      acc[ti][1] = (f32x4){0.f, 0.f, 0.f, 0.f};
    }
#pragma unroll
    for (int kb = 0; kb < 4; kb++) {
      short8 aF[4];
#pragma unroll
      for (int ti = 0; ti < 4; ti++)
        aF[ti] = *(const short8*)&XH[(ti * 16 + l15) * D +
                                     (((kb * 4 + quad) ^ l15) << 3)];
#pragma unroll
      for (int ti = 0; ti < 4; ti++) {
        acc[ti][0] = __builtin_amdgcn_mfma_f32_16x16x32_bf16(aF[ti], cW[kb][0],
                                                             acc[ti][0], 0, 0, 0);
        acc[ti][1] = __builtin_amdgcn_mfma_f32_16x16x32_bf16(aF[ti], cW[kb][1],
                                                             acc[ti][1], 0, 0, 0);
      }
    }

    // scatter stores (fp32, 64B segments per 16-lane group)
#pragma unroll
    for (int ti = 0; ti < 4; ti++)
#pragma unroll
      for (int rr = 0; rr < 4; rr++) {
        const int rl = ti * 16 + quad * 4 + rr;
        if (i0 + rl < cnt) {
          float* orow = out + (size_t)rowlist[i0 + rl] * D + w * 32 + l15;
          orow[0] = acc[ti][0][rr];
          orow[16] = acc[ti][1][rr];
        }
      }
  }
}

extern "C" void kernel_launch(void* const* d_in, const int* in_sizes, int n_in,
                              void* d_out, int out_size, void* d_ws, size_t ws_size,
                              hipStream_t stream) {
  const float* x = (const float*)d_in[0];
  const int* sidx = (const int*)d_in[1];
  const float* A_all = (const float*)d_in[2];
  const float* C_all = (const float*)d_in[3];
  float* out = (float*)d_out;

  // Wt needs 2*NS*D*D*2B = 1 MiB of workspace (ws is re-poisoned each reset;
  // prep_weights rewrites it every launch, so no cross-launch state).
  unsigned short* Wt = (unsigned short*)d_ws;

  prep_weights<<<128, 256, 0, stream>>>(A_all, C_all, Wt);
  ssm_mfma<<<512, 256, 0, stream>>>(x, sidx, Wt, out);
}